// Round 16
// baseline (46.885 us; speedup 1.0000x reference)
//
#include <hip/hip_runtime.h>
#include <hip/hip_bf16.h>
#include <math.h>

#define BATCH 2
#define CCH 64
#define WW 64
#define RR 32
#define HWD 4096
#define LOG2E 1.4426950408889634f

typedef __attribute__((ext_vector_type(8))) short bf16x8;
typedef __attribute__((ext_vector_type(4))) float f32x4;
typedef __attribute__((ext_vector_type(2))) unsigned int uint2v;
typedef __attribute__((ext_vector_type(4))) unsigned int uint4v;
typedef __attribute__((ext_vector_type(2))) float f32x2;

__device__ __forceinline__ ushort f2b(float x) {
    __hip_bfloat16 h = __float2bfloat16(x);
    return *reinterpret_cast<ushort*>(&h);
}
__device__ __forceinline__ uint pk2(float a, float b) {
    return (uint)f2b(a) | ((uint)f2b(b) << 16);
}
// truncating pack: 2 ALU ops for 2 values (RNE software path is ~12)
__device__ __forceinline__ uint pk2t(float a, float b) {
    uint ua = __builtin_bit_cast(uint, a);
    uint ub = __builtin_bit_cast(uint, b);
    return (ua >> 16) | (ub & 0xFFFF0000u);
}
__device__ __forceinline__ float fexp2(float x) {
#if __has_builtin(__builtin_amdgcn_exp2f)
    return __builtin_amdgcn_exp2f(x);
#else
    return exp2f(x);
#endif
}
__device__ __forceinline__ float b2f_lo(uint u) {
    return __builtin_bit_cast(float, u << 16);
}
__device__ __forceinline__ float b2f_hi(uint u) {
    return __builtin_bit_cast(float, u & 0xFFFF0000u);
}

// ---------------------------------------------------------------------------
// prep: 1x1 convs, 4-way r-split for occupancy (768 blocks).
// kind 0 -> theta*log2e [sb][4096][32] bf16 (+pre, +qadd)
// kind 1 -> phi   [sb][4096][32] bf16 (+kadd)
// kind 2 -> gT2   [sb][34][4096] bf16 (rows 32=ones, 33=col by rsplit 3)
// ---------------------------------------------------------------------------
__global__ __launch_bounds__(256) void prep_kernel(
    const float* __restrict__ left, const float* __restrict__ right,
    const float* __restrict__ pre_l, const float* __restrict__ pre_r,
    const float* __restrict__ query_l, const float* __restrict__ key_l,
    const float* __restrict__ query_r, const float* __restrict__ key_r,
    const float* __restrict__ w_theta, const float* __restrict__ b_theta,
    const float* __restrict__ w_phi, const float* __restrict__ b_phi,
    const float* __restrict__ w_g, const float* __restrict__ b_g,
    ushort* __restrict__ thetaB, ushort* __restrict__ phiB,
    ushort* __restrict__ gT2)
{
    __shared__ float w_s[64][8];
    __shared__ float wx_s[8];
    __shared__ float bias_s[8];
    int tid = threadIdx.x;
    int kind = blockIdx.x >> 8;            // 0..2
    int rem = blockIdx.x & 255;
    int rsplit = rem >> 6;                 // 0..3
    int pchunk = rem & 63;
    int r0 = rsplit * 8;

    const float* wsrc = (kind == 0) ? w_theta : ((kind == 1) ? w_phi : w_g);
    const float* bsrc = (kind == 0) ? b_theta : ((kind == 1) ? b_phi : b_g);
    int wld = (kind == 0) ? 65 : 64;
    for (int i = tid; i < 64 * 8; i += 256) {
        int rr = i >> 6, c = i & 63;
        w_s[c][rr] = wsrc[(size_t)(r0 + rr) * wld + c];
    }
    if (kind == 0 && tid < 8) wx_s[tid] = w_theta[(size_t)(r0 + tid) * 65 + 64];
    if (tid < 8) bias_s[tid] = bsrc[r0 + tid];
    __syncthreads();

    int t = pchunk * 256 + tid;            // 0..16383
    int sb = t >> 12;
    int side = sb >> 1;
    int b = sb & 1;
    int p = t & 4095;

    const float* X;
    if (kind == 0) X = side ? right : left;   // xq
    else           X = side ? left  : right;  // xk

    float acc[8];
    #pragma unroll
    for (int r = 0; r < 8; ++r) acc[r] = bias_s[r];

    const float* xp = X + (size_t)b * CCH * HWD + p;
    for (int c = 0; c < CCH; ++c) {
        float xv = xp[(size_t)c * HWD];
        #pragma unroll
        for (int r = 0; r < 8; ++r) acc[r] += w_s[c][r] * xv;
    }

    if (kind == 0) {
        const float* pre  = side ? pre_r   : pre_l;
        const float* qadd = side ? query_r : query_l;
        float pv = pre[(size_t)b * HWD + p] * (1.0f / 64.0f);
        uint4v u4;
        #pragma unroll
        for (int r = 0; r < 8; r += 2) {
            float v0 = (acc[r]   + wx_s[r]   * pv + qadd[((size_t)b * RR + r0 + r)   * HWD + p]) * LOG2E;
            float v1 = (acc[r+1] + wx_s[r+1] * pv + qadd[((size_t)b * RR + r0 + r+1) * HWD + p]) * LOG2E;
            u4[r >> 1] = pk2(v0, v1);
        }
        *(uint4v*)(thetaB + (size_t)t * RR + r0) = u4;
    } else if (kind == 1) {
        const float* kadd = side ? key_l : key_r;
        uint4v u4;
        #pragma unroll
        for (int r = 0; r < 8; r += 2) {
            float v0 = acc[r]   + kadd[((size_t)b * RR + r0 + r)   * HWD + p];
            float v1 = acc[r+1] + kadd[((size_t)b * RR + r0 + r+1) * HWD + p];
            u4[r >> 1] = pk2(v0, v1);
        }
        *(uint4v*)(phiB + (size_t)t * RR + r0) = u4;
    } else {
        ushort* gdst = gT2 + (size_t)sb * 34 * HWD + p;
        #pragma unroll
        for (int r = 0; r < 8; ++r) gdst[(size_t)(r0 + r) * HWD] = f2b(acc[r]);
        if (rsplit == 3) {
            gdst[(size_t)32 * HWD] = 0x3F80;               // 1.0 bf16
            gdst[(size_t)33 * HWD] = f2b((float)(p & 63)); // col
        }
    }
}

// ---------------------------------------------------------------------------
// attn: 512 blocks x 512 thr, launch_bounds(512,4) -> 2 blocks/CU target.
// Block = (sb, q-pair of 32) via XCD swizzle: xcd = bid&7, sb = xcd>>1,
// qquad = (bid>>3)|((xcd&1)<<6). 8 waves = key splits of 512; 2 q-tiles/wave.
// phi fragments software-prefetched one kb ahead; setprio around compute.
// ---------------------------------------------------------------------------
__global__ __launch_bounds__(512, 4) void attn_kernel(
    const ushort* __restrict__ thetaB, const ushort* __restrict__ phiB,
    const ushort* __restrict__ gT2,
    const float* __restrict__ w_up, const float* __restrict__ b_up,
    ushort* __restrict__ yB, float* __restrict__ part,
    float* __restrict__ d_out)
{
    __shared__ __attribute__((aligned(16))) char smem[23168];
    auto accbuf = reinterpret_cast<float(*)[2][34][17]>(smem);   // [4][2][34][17] = 18,496 B
    float* a_s  = (float*)(smem + 18560);                        // [32][36] = 4608 B

    int tid = threadIdx.x;
    int w = tid >> 6, l = tid & 63;
    int ql = l & 15, kgrp = l >> 4;
    int bid = blockIdx.x;                  // 512 blocks
    int xcd = bid & 7;
    int sb = xcd >> 1;                     // 0..3 (2 XCDs per sb)
    int qquad = (bid >> 3) | ((xcd & 1) << 6);   // 0..127
    int lblk = (sb << 7) | qquad;          // logical block for part indexing
    int q0 = qquad * 32;

    const ushort* thb = thetaB + (size_t)sb * HWD * RR;
    const ushort* phb = phiB + (size_t)sb * HWD * RR;
    const ushort* gtb = gT2 + (size_t)sb * 34 * HWD;

    bf16x8 bf[2];
    #pragma unroll
    for (int qt = 0; qt < 2; ++qt)
        bf[qt] = *(const bf16x8*)(thb + (size_t)(q0 + 16 * qt + ql) * RR + kgrp * 8);

    const f32x4 zf = {0.f, 0.f, 0.f, 0.f};
    f32x4 accA_[2], accB_[2], accC_[2];
    #pragma unroll
    for (int qt = 0; qt < 2; ++qt) { accA_[qt] = zf; accB_[qt] = zf; accC_[qt] = zf; }

    int grow2 = (ql == 0) ? 32 : 33;

    // prefetch phi frags for kb=0
    const ushort* ph0 = phb + (size_t)(w * 512 + ql) * RR + kgrp * 8;
    bf16x8 p00 = *(const bf16x8*)(ph0);
    bf16x8 p01 = *(const bf16x8*)(ph0 + (size_t)16 * RR);
    bf16x8 p10 = *(const bf16x8*)(ph0 + (size_t)32 * RR);
    bf16x8 p11 = *(const bf16x8*)(ph0 + (size_t)48 * RR);

    for (int kb = 0; kb < 8; ++kb) {
        int kbase = w * 512 + kb * 64;

        // g loads (natural coverage: consumed after QK+exp+pack)
        const ushort* gp = gtb + kbase + kgrp * 8;
        bf16x8 g00 = *(const bf16x8*)(gp + (size_t)ql * HWD);
        bf16x8 g10 = *(const bf16x8*)(gp + (size_t)(16 + ql) * HWD);
        bf16x8 g20 = *(const bf16x8*)(gp + (size_t)grow2 * HWD);
        bf16x8 g01 = *(const bf16x8*)(gp + (size_t)ql * HWD + 32);
        bf16x8 g11 = *(const bf16x8*)(gp + (size_t)(16 + ql) * HWD + 32);
        bf16x8 g21 = *(const bf16x8*)(gp + (size_t)grow2 * HWD + 32);

        // prefetch next kb's phi frags (full compute phase of latency coverage)
        bf16x8 n00, n01, n10, n11;
        if (kb < 7) {
            const ushort* phn = phb + (size_t)(kbase + 64 + ql) * RR + kgrp * 8;
            n00 = *(const bf16x8*)(phn);
            n01 = *(const bf16x8*)(phn + (size_t)16 * RR);
            n10 = *(const bf16x8*)(phn + (size_t)32 * RR);
            n11 = *(const bf16x8*)(phn + (size_t)48 * RR);
        }

        __builtin_amdgcn_s_setprio(1);
        #pragma unroll
        for (int jp = 0; jp < 2; ++jp) {
            bf16x8 aphi0 = jp ? p10 : p00;
            bf16x8 aphi1 = jp ? p11 : p01;
            bf16x8 ga = jp ? g01 : g00;
            bf16x8 gb = jp ? g11 : g10;
            bf16x8 gc = jp ? g21 : g20;
            #pragma unroll
            for (int qt = 0; qt < 2; ++qt) {
                f32x4 s0 = __builtin_amdgcn_mfma_f32_16x16x32_bf16(aphi0, bf[qt], zf, 0, 0, 0);
                f32x4 s1 = __builtin_amdgcn_mfma_f32_16x16x32_bf16(aphi1, bf[qt], zf, 0, 0, 0);
                uint a0 = pk2t(fexp2(s0[0]), fexp2(s0[1]));
                uint a1 = pk2t(fexp2(s0[2]), fexp2(s0[3]));
                uint b0 = pk2t(fexp2(s1[0]), fexp2(s1[1]));
                uint b1 = pk2t(fexp2(s1[2]), fexp2(s1[3]));
                uint2v A = __builtin_amdgcn_permlane32_swap(a0, b0, false, false);
                uint2v B = __builtin_amdgcn_permlane32_swap(a1, b1, false, false);
                uint2v C = __builtin_amdgcn_permlane16_swap(A[0], A[1], false, false);
                uint2v D = __builtin_amdgcn_permlane16_swap(B[0], B[1], false, false);
                union { bf16x8 v; uint u[4]; } pb;
                pb.u[0] = C[0]; pb.u[1] = D[0]; pb.u[2] = C[1]; pb.u[3] = D[1];
                accA_[qt] = __builtin_amdgcn_mfma_f32_16x16x32_bf16(ga, pb.v, accA_[qt], 0, 0, 0);
                accB_[qt] = __builtin_amdgcn_mfma_f32_16x16x32_bf16(gb, pb.v, accB_[qt], 0, 0, 0);
                accC_[qt] = __builtin_amdgcn_mfma_f32_16x16x32_bf16(gc, pb.v, accC_[qt], 0, 0, 0);
            }
        }
        __builtin_amdgcn_s_setprio(0);

        if (kb < 7) { p00 = n00; p01 = n01; p10 = n10; p11 = n11; }
    }

    __syncthreads();

    if (w < 4) {
        #pragma unroll
        for (int qt = 0; qt < 2; ++qt) {
            #pragma unroll
            for (int r = 0; r < 4; ++r) {
                accbuf[w][qt][4 * kgrp + r][ql] = accA_[qt][r];
                accbuf[w][qt][16 + 4 * kgrp + r][ql] = accB_[qt][r];
            }
            if (kgrp == 0) {
                accbuf[w][qt][32][ql] = accC_[qt][0];
                accbuf[w][qt][33][ql] = accC_[qt][1];
            }
        }
    }
    __syncthreads();

    if (w >= 4) {
        int wd = w - 4;
        #pragma unroll
        for (int qt = 0; qt < 2; ++qt) {
            #pragma unroll
            for (int r = 0; r < 4; ++r) {
                accbuf[wd][qt][4 * kgrp + r][ql] += accA_[qt][r];
                accbuf[wd][qt][16 + 4 * kgrp + r][ql] += accB_[qt][r];
            }
            if (kgrp == 0) {
                accbuf[wd][qt][32][ql] += accC_[qt][0];
                accbuf[wd][qt][33][ql] += accC_[qt][1];
            }
        }
    }
    __syncthreads();

    // reduce 4 buffers; a -> a_s; index row 33 -> d_out
    for (int i = tid; i < 2 * 34 * 16; i += 512) {
        int qt = i / 544, rem = i % 544;
        int rp = rem >> 4, qq = rem & 15;
        float v = 0.f, s = 0.f;
        #pragma unroll
        for (int ww = 0; ww < 4; ++ww) {
            v += accbuf[ww][qt][rp][qq];
            s += accbuf[ww][qt][32][qq];
        }
        int Q = q0 + qt * 16 + qq;
        if (rp < 32) {
            a_s[(qt * 16 + qq) * 36 + rp] = v / s;
        } else if (rp == 33) {
            d_out[(size_t)2 * BATCH * CCH * HWD + (size_t)sb * HWD + Q] =
                (float)(Q & 63) - v / s;
        }
    }
    __syncthreads();

    // fused up-conv: y[o][q] = b_up[o] + sum_r wup[o][r] * a[q][r]
    // thread (o, qg) handles q = qg*4 + j; y -> bf16
    {
        int o = tid >> 3, qg = tid & 7;
        float bu = b_up[o];
        const float* wrow = w_up + o * RR;
        float yv[4] = {bu, bu, bu, bu};
        #pragma unroll
        for (int r4 = 0; r4 < 8; ++r4) {
            f32x4 wv = *(const f32x4*)(wrow + r4 * 4);
            #pragma unroll
            for (int j = 0; j < 4; ++j) {
                f32x4 av = *(const f32x4*)(a_s + (qg * 4 + j) * 36 + r4 * 4);
                yv[j] += av[0] * wv[0] + av[1] * wv[1] + av[2] * wv[2] + av[3] * wv[3];
            }
        }
        float s1 = yv[0] + yv[1] + yv[2] + yv[3];
        float s2 = yv[0]*yv[0] + yv[1]*yv[1] + yv[2]*yv[2] + yv[3]*yv[3];
        uint2v y2;
        y2[0] = pk2(yv[0], yv[1]);
        y2[1] = pk2(yv[2], yv[3]);
        *(uint2v*)(yB + (((size_t)sb * 64 + o) << 12) + q0 + qg * 4) = y2;
        #pragma unroll
        for (int m = 1; m < 8; m <<= 1) {
            s1 += __shfl_xor(s1, m, 8);
            s2 += __shfl_xor(s2, m, 8);
        }
        if (qg == 0) {
            *(f32x2*)(part + ((size_t)lblk * 64 + o) * 2) = f32x2{s1, s2};
        }
    }
}

// ---------------------------------------------------------------------------
// apply: block = (side,b,o,half). Finalize BN scale/shift from part
// (256 logical-block partials per side, no LDS), then
// out = x + y*scale + shift  (y read as bf16, unpacked via <<16)
// ---------------------------------------------------------------------------
__global__ __launch_bounds__(256) void apply_kernel(
    const float* __restrict__ left, const float* __restrict__ right,
    const ushort* __restrict__ yB, const float* __restrict__ part,
    const float* __restrict__ gamma, const float* __restrict__ beta,
    float* __restrict__ d_out)
{
    int bid = blockIdx.x;                  // 512: side|b|o|half
    int side = bid >> 8, b = (bid >> 7) & 1, o = (bid >> 1) & 63, half = bid & 1;
    int tid = threadIdx.x;
    int l = tid & 63;

    // finalize: sum this side's 256 logical-block partials for channel o
    const f32x2* pp = (const f32x2*)part;
    float s1 = 0.f, s2 = 0.f;
    #pragma unroll
    for (int i = 0; i < 4; ++i) {
        f32x2 v = pp[((size_t)(side * 256 + i * 64 + l)) * 64 + o];
        s1 += v[0]; s2 += v[1];
    }
    #pragma unroll
    for (int m = 1; m < 64; m <<= 1) {
        s1 += __shfl_xor(s1, m);
        s2 += __shfl_xor(s2, m);
    }
    float n = (float)(BATCH * HWD);
    float mean = s1 / n;
    float var = s2 / n - mean * mean;
    float scale = gamma[o] / sqrtf(var + 1e-5f);
    float shift = beta[o] - mean * scale;

    const float* x = side ? right : left;
    const uint2v* yp = (const uint2v*)(yB + (((size_t)(side * 2 + b) * 64 + o) << 12));
    const f32x4* xp = (const f32x4*)(x + (((size_t)b * 64 + o) << 12));
    f32x4* op = (f32x4*)(d_out + (size_t)side * (BATCH * CCH * HWD)
                         + (((size_t)b * 64 + o) << 12));

    #pragma unroll
    for (int i = 0; i < 2; ++i) {
        int idx = half * 512 + tid + i * 256;
        uint2v yu = yp[idx];
        f32x4 xv = xp[idx];
        f32x4 ov;
        ov[0] = xv[0] + b2f_lo(yu[0]) * scale + shift;
        ov[1] = xv[1] + b2f_hi(yu[0]) * scale + shift;
        ov[2] = xv[2] + b2f_lo(yu[1]) * scale + shift;
        ov[3] = xv[3] + b2f_hi(yu[1]) * scale + shift;
        op[idx] = ov;
    }
}

extern "C" void kernel_launch(void* const* d_in, const int* in_sizes, int n_in,
                              void* d_out, int out_size, void* d_ws, size_t ws_size,
                              hipStream_t stream)
{
    const float* left    = (const float*)d_in[0];
    const float* right   = (const float*)d_in[1];
    const float* pre_l   = (const float*)d_in[2];
    const float* pre_r   = (const float*)d_in[3];
    const float* query_l = (const float*)d_in[4];
    const float* key_l   = (const float*)d_in[5];
    const float* query_r = (const float*)d_in[6];
    const float* key_r   = (const float*)d_in[7];
    const float* w_theta = (const float*)d_in[8];
    const float* b_theta = (const float*)d_in[9];
    const float* w_phi   = (const float*)d_in[10];
    const float* b_phi   = (const float*)d_in[11];
    const float* w_g     = (const float*)d_in[12];
    const float* b_g     = (const float*)d_in[13];
    const float* w_up    = (const float*)d_in[14];
    const float* b_up    = (const float*)d_in[15];
    const float* gamma   = (const float*)d_in[16];
    const float* beta    = (const float*)d_in[17];

    char* ws = (char*)d_ws;
    ushort* thetaB  = (ushort*)ws;                       // 1,048,576
    ushort* phiB    = (ushort*)(ws + 1048576);           // 1,048,576
    ushort* gT2     = (ushort*)(ws + 2097152);           // 1,114,112
    ushort* yB      = (ushort*)(ws + 3211264);           // 2,097,152 (bf16)
    float*  part    = (float*)(ws + 5308416);            // 262,144

    prep_kernel<<<768, 256, 0, stream>>>(left, right, pre_l, pre_r,
                                         query_l, key_l, query_r, key_r,
                                         w_theta, b_theta, w_phi, b_phi,
                                         w_g, b_g, thetaB, phiB, gT2);
    attn_kernel<<<512, 512, 0, stream>>>(thetaB, phiB, gT2, w_up, b_up,
                                         yB, part, (float*)d_out);
    apply_kernel<<<512, 256, 0, stream>>>(left, right, yB, part,
                                          gamma, beta, (float*)d_out);
}

// Round 17
// 37.017 us; speedup vs baseline: 1.2666x; 1.2666x over previous
//
#include <hip/hip_runtime.h>
#include <hip/hip_bf16.h>
#include <math.h>

#define BATCH 2
#define CCH 64
#define WW 64
#define RR 32
#define HWD 4096
#define LOG2E 1.4426950408889634f

typedef __attribute__((ext_vector_type(8))) short bf16x8;
typedef __attribute__((ext_vector_type(4))) float f32x4;
typedef __attribute__((ext_vector_type(2))) unsigned int uint2v;
typedef __attribute__((ext_vector_type(4))) unsigned int uint4v;
typedef __attribute__((ext_vector_type(2))) float f32x2;

__device__ __forceinline__ ushort f2b(float x) {
    __hip_bfloat16 h = __float2bfloat16(x);
    return *reinterpret_cast<ushort*>(&h);
}
__device__ __forceinline__ uint pk2(float a, float b) {
    return (uint)f2b(a) | ((uint)f2b(b) << 16);
}
// truncating pack: 2 ALU ops for 2 values (RNE software path is ~12)
__device__ __forceinline__ uint pk2t(float a, float b) {
    uint ua = __builtin_bit_cast(uint, a);
    uint ub = __builtin_bit_cast(uint, b);
    return (ua >> 16) | (ub & 0xFFFF0000u);
}
__device__ __forceinline__ float fexp2(float x) {
#if __has_builtin(__builtin_amdgcn_exp2f)
    return __builtin_amdgcn_exp2f(x);
#else
    return exp2f(x);
#endif
}
__device__ __forceinline__ float b2f_lo(uint u) {
    return __builtin_bit_cast(float, u << 16);
}
__device__ __forceinline__ float b2f_hi(uint u) {
    return __builtin_bit_cast(float, u & 0xFFFF0000u);
}

// ---------------------------------------------------------------------------
// prep: 1x1 convs, 4-way r-split for occupancy (768 blocks).
// kind 0 -> theta*log2e [sb][4096][32] bf16 (+pre, +qadd)
// kind 1 -> phi   [sb][4096][32] bf16 (+kadd)
// kind 2 -> gT2   [sb][34][4096] bf16 (rows 32=ones, 33=col by rsplit 3)
// ---------------------------------------------------------------------------
__global__ __launch_bounds__(256) void prep_kernel(
    const float* __restrict__ left, const float* __restrict__ right,
    const float* __restrict__ pre_l, const float* __restrict__ pre_r,
    const float* __restrict__ query_l, const float* __restrict__ key_l,
    const float* __restrict__ query_r, const float* __restrict__ key_r,
    const float* __restrict__ w_theta, const float* __restrict__ b_theta,
    const float* __restrict__ w_phi, const float* __restrict__ b_phi,
    const float* __restrict__ w_g, const float* __restrict__ b_g,
    ushort* __restrict__ thetaB, ushort* __restrict__ phiB,
    ushort* __restrict__ gT2)
{
    __shared__ float w_s[64][8];
    __shared__ float wx_s[8];
    __shared__ float bias_s[8];
    int tid = threadIdx.x;
    int kind = blockIdx.x >> 8;            // 0..2
    int rem = blockIdx.x & 255;
    int rsplit = rem >> 6;                 // 0..3
    int pchunk = rem & 63;
    int r0 = rsplit * 8;

    const float* wsrc = (kind == 0) ? w_theta : ((kind == 1) ? w_phi : w_g);
    const float* bsrc = (kind == 0) ? b_theta : ((kind == 1) ? b_phi : b_g);
    int wld = (kind == 0) ? 65 : 64;
    for (int i = tid; i < 64 * 8; i += 256) {
        int rr = i >> 6, c = i & 63;
        w_s[c][rr] = wsrc[(size_t)(r0 + rr) * wld + c];
    }
    if (kind == 0 && tid < 8) wx_s[tid] = w_theta[(size_t)(r0 + tid) * 65 + 64];
    if (tid < 8) bias_s[tid] = bsrc[r0 + tid];
    __syncthreads();

    int t = pchunk * 256 + tid;            // 0..16383
    int sb = t >> 12;
    int side = sb >> 1;
    int b = sb & 1;
    int p = t & 4095;

    const float* X;
    if (kind == 0) X = side ? right : left;   // xq
    else           X = side ? left  : right;  // xk

    float acc[8];
    #pragma unroll
    for (int r = 0; r < 8; ++r) acc[r] = bias_s[r];

    const float* xp = X + (size_t)b * CCH * HWD + p;
    for (int c = 0; c < CCH; ++c) {
        float xv = xp[(size_t)c * HWD];
        #pragma unroll
        for (int r = 0; r < 8; ++r) acc[r] += w_s[c][r] * xv;
    }

    if (kind == 0) {
        const float* pre  = side ? pre_r   : pre_l;
        const float* qadd = side ? query_r : query_l;
        float pv = pre[(size_t)b * HWD + p] * (1.0f / 64.0f);
        uint4v u4;
        #pragma unroll
        for (int r = 0; r < 8; r += 2) {
            float v0 = (acc[r]   + wx_s[r]   * pv + qadd[((size_t)b * RR + r0 + r)   * HWD + p]) * LOG2E;
            float v1 = (acc[r+1] + wx_s[r+1] * pv + qadd[((size_t)b * RR + r0 + r+1) * HWD + p]) * LOG2E;
            u4[r >> 1] = pk2(v0, v1);
        }
        *(uint4v*)(thetaB + (size_t)t * RR + r0) = u4;
    } else if (kind == 1) {
        const float* kadd = side ? key_l : key_r;
        uint4v u4;
        #pragma unroll
        for (int r = 0; r < 8; r += 2) {
            float v0 = acc[r]   + kadd[((size_t)b * RR + r0 + r)   * HWD + p];
            float v1 = acc[r+1] + kadd[((size_t)b * RR + r0 + r+1) * HWD + p];
            u4[r >> 1] = pk2(v0, v1);
        }
        *(uint4v*)(phiB + (size_t)t * RR + r0) = u4;
    } else {
        ushort* gdst = gT2 + (size_t)sb * 34 * HWD + p;
        #pragma unroll
        for (int r = 0; r < 8; ++r) gdst[(size_t)(r0 + r) * HWD] = f2b(acc[r]);
        if (rsplit == 3) {
            gdst[(size_t)32 * HWD] = 0x3F80;               // 1.0 bf16
            gdst[(size_t)33 * HWD] = f2b((float)(p & 63)); // col
        }
    }
}

// ---------------------------------------------------------------------------
// attn: 256 blocks x 512 thr. Block = (sb, q-quad of 64) via XCD swizzle.
// 8 waves = key splits of 512; each wave: 4 q-tiles (phi/g frags shared).
// phi fragments software-prefetched one kb ahead (QK consumes them with no
// natural latency coverage); s_setprio(1) around the MFMA/exp cluster.
// ---------------------------------------------------------------------------
__global__ __launch_bounds__(512, 2) void attn_kernel(
    const ushort* __restrict__ thetaB, const ushort* __restrict__ phiB,
    const ushort* __restrict__ gT2,
    const float* __restrict__ w_up, const float* __restrict__ b_up,
    ushort* __restrict__ yB, float* __restrict__ part,
    float* __restrict__ d_out)
{
    __shared__ __attribute__((aligned(16))) char smem[46208];
    auto accbuf = reinterpret_cast<float(*)[4][34][17]>(smem);   // [4][4][34][17] = 36,992 B
    float* a_s  = (float*)(smem + 36992);                        // [64][36] = 9216 B

    int tid = threadIdx.x;
    int w = tid >> 6, l = tid & 63;
    int ql = l & 15, kgrp = l >> 4;
    int bid = blockIdx.x;                  // 256 blocks
    int xcd = bid & 7;
    int sb = xcd >> 1;                     // 0..3 (one sb per XCD pair)
    int qquad = (bid >> 3) | ((xcd & 1) << 5);   // 0..63
    int lblk = (sb << 6) | qquad;          // logical block for part indexing
    int q0 = qquad * 64;

    const ushort* thb = thetaB + (size_t)sb * HWD * RR;
    const ushort* phb = phiB + (size_t)sb * HWD * RR;
    const ushort* gtb = gT2 + (size_t)sb * 34 * HWD;

    bf16x8 bf[4];
    #pragma unroll
    for (int qt = 0; qt < 4; ++qt)
        bf[qt] = *(const bf16x8*)(thb + (size_t)(q0 + 16 * qt + ql) * RR + kgrp * 8);

    const f32x4 zf = {0.f, 0.f, 0.f, 0.f};
    f32x4 accA_[4], accB_[4], accC_[4];
    #pragma unroll
    for (int qt = 0; qt < 4; ++qt) { accA_[qt] = zf; accB_[qt] = zf; accC_[qt] = zf; }

    int grow2 = (ql == 0) ? 32 : 33;

    // prefetch phi frags for kb=0
    const ushort* ph0 = phb + (size_t)(w * 512 + ql) * RR + kgrp * 8;
    bf16x8 p00 = *(const bf16x8*)(ph0);
    bf16x8 p01 = *(const bf16x8*)(ph0 + (size_t)16 * RR);
    bf16x8 p10 = *(const bf16x8*)(ph0 + (size_t)32 * RR);
    bf16x8 p11 = *(const bf16x8*)(ph0 + (size_t)48 * RR);

    for (int kb = 0; kb < 8; ++kb) {
        int kbase = w * 512 + kb * 64;

        // g loads (natural coverage: consumed after QK+exp+pack)
        const ushort* gp = gtb + kbase + kgrp * 8;
        bf16x8 g00 = *(const bf16x8*)(gp + (size_t)ql * HWD);
        bf16x8 g10 = *(const bf16x8*)(gp + (size_t)(16 + ql) * HWD);
        bf16x8 g20 = *(const bf16x8*)(gp + (size_t)grow2 * HWD);
        bf16x8 g01 = *(const bf16x8*)(gp + (size_t)ql * HWD + 32);
        bf16x8 g11 = *(const bf16x8*)(gp + (size_t)(16 + ql) * HWD + 32);
        bf16x8 g21 = *(const bf16x8*)(gp + (size_t)grow2 * HWD + 32);

        // prefetch next kb's phi frags (issued before compute -> full phase of coverage)
        bf16x8 n00, n01, n10, n11;
        if (kb < 7) {
            const ushort* phn = phb + (size_t)(kbase + 64 + ql) * RR + kgrp * 8;
            n00 = *(const bf16x8*)(phn);
            n01 = *(const bf16x8*)(phn + (size_t)16 * RR);
            n10 = *(const bf16x8*)(phn + (size_t)32 * RR);
            n11 = *(const bf16x8*)(phn + (size_t)48 * RR);
        }

        __builtin_amdgcn_s_setprio(1);
        #pragma unroll
        for (int jp = 0; jp < 2; ++jp) {
            bf16x8 aphi0 = jp ? p10 : p00;
            bf16x8 aphi1 = jp ? p11 : p01;
            bf16x8 ga = jp ? g01 : g00;
            bf16x8 gb = jp ? g11 : g10;
            bf16x8 gc = jp ? g21 : g20;
            #pragma unroll
            for (int qt = 0; qt < 4; ++qt) {
                f32x4 s0 = __builtin_amdgcn_mfma_f32_16x16x32_bf16(aphi0, bf[qt], zf, 0, 0, 0);
                f32x4 s1 = __builtin_amdgcn_mfma_f32_16x16x32_bf16(aphi1, bf[qt], zf, 0, 0, 0);
                uint a0 = pk2t(fexp2(s0[0]), fexp2(s0[1]));
                uint a1 = pk2t(fexp2(s0[2]), fexp2(s0[3]));
                uint b0 = pk2t(fexp2(s1[0]), fexp2(s1[1]));
                uint b1 = pk2t(fexp2(s1[2]), fexp2(s1[3]));
                uint2v A = __builtin_amdgcn_permlane32_swap(a0, b0, false, false);
                uint2v B = __builtin_amdgcn_permlane32_swap(a1, b1, false, false);
                uint2v C = __builtin_amdgcn_permlane16_swap(A[0], A[1], false, false);
                uint2v D = __builtin_amdgcn_permlane16_swap(B[0], B[1], false, false);
                union { bf16x8 v; uint u[4]; } pb;
                pb.u[0] = C[0]; pb.u[1] = D[0]; pb.u[2] = C[1]; pb.u[3] = D[1];
                accA_[qt] = __builtin_amdgcn_mfma_f32_16x16x32_bf16(ga, pb.v, accA_[qt], 0, 0, 0);
                accB_[qt] = __builtin_amdgcn_mfma_f32_16x16x32_bf16(gb, pb.v, accB_[qt], 0, 0, 0);
                accC_[qt] = __builtin_amdgcn_mfma_f32_16x16x32_bf16(gc, pb.v, accC_[qt], 0, 0, 0);
            }
        }
        __builtin_amdgcn_s_setprio(0);

        if (kb < 7) { p00 = n00; p01 = n01; p10 = n10; p11 = n11; }
    }

    __syncthreads();

    if (w < 4) {
        #pragma unroll
        for (int qt = 0; qt < 4; ++qt) {
            #pragma unroll
            for (int r = 0; r < 4; ++r) {
                accbuf[w][qt][4 * kgrp + r][ql] = accA_[qt][r];
                accbuf[w][qt][16 + 4 * kgrp + r][ql] = accB_[qt][r];
            }
            if (kgrp == 0) {
                accbuf[w][qt][32][ql] = accC_[qt][0];
                accbuf[w][qt][33][ql] = accC_[qt][1];
            }
        }
    }
    __syncthreads();

    if (w >= 4) {
        int wd = w - 4;
        #pragma unroll
        for (int qt = 0; qt < 4; ++qt) {
            #pragma unroll
            for (int r = 0; r < 4; ++r) {
                accbuf[wd][qt][4 * kgrp + r][ql] += accA_[qt][r];
                accbuf[wd][qt][16 + 4 * kgrp + r][ql] += accB_[qt][r];
            }
            if (kgrp == 0) {
                accbuf[wd][qt][32][ql] += accC_[qt][0];
                accbuf[wd][qt][33][ql] += accC_[qt][1];
            }
        }
    }
    __syncthreads();

    // reduce 4 buffers; a -> a_s; index row 33 -> d_out
    for (int i = tid; i < 4 * 34 * 16; i += 512) {
        int qt = i / 544, rem = i % 544;
        int rp = rem >> 4, qq = rem & 15;
        float v = 0.f, s = 0.f;
        #pragma unroll
        for (int ww = 0; ww < 4; ++ww) {
            v += accbuf[ww][qt][rp][qq];
            s += accbuf[ww][qt][32][qq];
        }
        int Q = q0 + qt * 16 + qq;
        if (rp < 32) {
            a_s[(qt * 16 + qq) * 36 + rp] = v / s;
        } else if (rp == 33) {
            d_out[(size_t)2 * BATCH * CCH * HWD + (size_t)sb * HWD + Q] =
                (float)(Q & 63) - v / s;
        }
    }
    __syncthreads();

    // fused up-conv: y[o][q] = b_up[o] + sum_r wup[o][r] * a[q][r]
    // thread (o, qg) handles q = half*32 + qg*4 + j for half 0..1; y -> bf16
    {
        int o = tid >> 3, qg = tid & 7;
        float bu = b_up[o];
        const float* wrow = w_up + o * RR;
        float s1 = 0.f, s2 = 0.f;
        #pragma unroll
        for (int half = 0; half < 2; ++half) {
            float yv[4] = {bu, bu, bu, bu};
            #pragma unroll
            for (int r4 = 0; r4 < 8; ++r4) {
                f32x4 wv = *(const f32x4*)(wrow + r4 * 4);
                #pragma unroll
                for (int j = 0; j < 4; ++j) {
                    f32x4 av = *(const f32x4*)(a_s + (half * 32 + qg * 4 + j) * 36 + r4 * 4);
                    yv[j] += av[0] * wv[0] + av[1] * wv[1] + av[2] * wv[2] + av[3] * wv[3];
                }
            }
            s1 += yv[0] + yv[1] + yv[2] + yv[3];
            s2 += yv[0]*yv[0] + yv[1]*yv[1] + yv[2]*yv[2] + yv[3]*yv[3];
            uint2v y2;
            y2[0] = pk2(yv[0], yv[1]);
            y2[1] = pk2(yv[2], yv[3]);
            *(uint2v*)(yB + (((size_t)sb * 64 + o) << 12) + q0 + half * 32 + qg * 4) = y2;
        }
        #pragma unroll
        for (int m = 1; m < 8; m <<= 1) {
            s1 += __shfl_xor(s1, m, 8);
            s2 += __shfl_xor(s2, m, 8);
        }
        if (qg == 0) {
            *(f32x2*)(part + ((size_t)lblk * 64 + o) * 2) = f32x2{s1, s2};
        }
    }
}

// ---------------------------------------------------------------------------
// apply: XCD-aligned decode — bid&7 = (side<<2)|(b<<1)|half so each XCD's
// apply blocks read the yB slice written by attn blocks on that same XCD
// (attn qquad bit5 = xcd parity => half-ranges are XCD-resident).
// Finalize BN scale/shift from part (128 partials/side), then
// out = x + y*scale + shift  (y read as bf16, unpacked via <<16)
// ---------------------------------------------------------------------------
__global__ __launch_bounds__(256) void apply_kernel(
    const float* __restrict__ left, const float* __restrict__ right,
    const ushort* __restrict__ yB, const float* __restrict__ part,
    const float* __restrict__ gamma, const float* __restrict__ beta,
    float* __restrict__ d_out)
{
    int bid = blockIdx.x;                  // 512: o | (side,b,half) in low 3 bits
    int xcd = bid & 7;
    int side = xcd >> 2, b = (xcd >> 1) & 1, half = xcd & 1;
    int o = bid >> 3;
    int tid = threadIdx.x;
    int l = tid & 63;

    // finalize: sum this side's 128 logical-block partials for channel o
    const f32x2* pp = (const f32x2*)part;
    f32x2 v1 = pp[((size_t)(side * 128 + l)) * 64 + o];
    f32x2 v2 = pp[((size_t)(side * 128 + 64 + l)) * 64 + o];
    float s1 = v1[0] + v2[0], s2 = v1[1] + v2[1];
    #pragma unroll
    for (int m = 1; m < 64; m <<= 1) {
        s1 += __shfl_xor(s1, m);
        s2 += __shfl_xor(s2, m);
    }
    float n = (float)(BATCH * HWD);
    float mean = s1 / n;
    float var = s2 / n - mean * mean;
    float scale = gamma[o] / sqrtf(var + 1e-5f);
    float shift = beta[o] - mean * scale;

    const float* x = side ? right : left;
    const uint2v* yp = (const uint2v*)(yB + (((size_t)(side * 2 + b) * 64 + o) << 12));
    const f32x4* xp = (const f32x4*)(x + (((size_t)b * 64 + o) << 12));
    f32x4* op = (f32x4*)(d_out + (size_t)side * (BATCH * CCH * HWD)
                         + (((size_t)b * 64 + o) << 12));

    #pragma unroll
    for (int i = 0; i < 2; ++i) {
        int idx = half * 512 + tid + i * 256;
        uint2v yu = yp[idx];
        f32x4 xv = xp[idx];
        f32x4 ov;
        ov[0] = xv[0] + b2f_lo(yu[0]) * scale + shift;
        ov[1] = xv[1] + b2f_hi(yu[0]) * scale + shift;
        ov[2] = xv[2] + b2f_lo(yu[1]) * scale + shift;
        ov[3] = xv[3] + b2f_hi(yu[1]) * scale + shift;
        op[idx] = ov;
    }
}

extern "C" void kernel_launch(void* const* d_in, const int* in_sizes, int n_in,
                              void* d_out, int out_size, void* d_ws, size_t ws_size,
                              hipStream_t stream)
{
    const float* left    = (const float*)d_in[0];
    const float* right   = (const float*)d_in[1];
    const float* pre_l   = (const float*)d_in[2];
    const float* pre_r   = (const float*)d_in[3];
    const float* query_l = (const float*)d_in[4];
    const float* key_l   = (const float*)d_in[5];
    const float* query_r = (const float*)d_in[6];
    const float* key_r   = (const float*)d_in[7];
    const float* w_theta = (const float*)d_in[8];
    const float* b_theta = (const float*)d_in[9];
    const float* w_phi   = (const float*)d_in[10];
    const float* b_phi   = (const float*)d_in[11];
    const float* w_g     = (const float*)d_in[12];
    const float* b_g     = (const float*)d_in[13];
    const float* w_up    = (const float*)d_in[14];
    const float* b_up    = (const float*)d_in[15];
    const float* gamma   = (const float*)d_in[16];
    const float* beta    = (const float*)d_in[17];

    char* ws = (char*)d_ws;
    ushort* thetaB  = (ushort*)ws;                       // 1,048,576
    ushort* phiB    = (ushort*)(ws + 1048576);           // 1,048,576
    ushort* gT2     = (ushort*)(ws + 2097152);           // 1,114,112
    ushort* yB      = (ushort*)(ws + 3211264);           // 2,097,152 (bf16)
    float*  part    = (float*)(ws + 5308416);            // 131,072

    prep_kernel<<<768, 256, 0, stream>>>(left, right, pre_l, pre_r,
                                         query_l, key_l, query_r, key_r,
                                         w_theta, b_theta, w_phi, b_phi,
                                         w_g, b_g, thetaB, phiB, gT2);
    attn_kernel<<<256, 512, 0, stream>>>(thetaB, phiB, gT2, w_up, b_up,
                                         yB, part, (float*)d_out);
    apply_kernel<<<512, 256, 0, stream>>>(left, right, yB, part,
                                          gamma, beta, (float*)d_out);
}